// Round 4
// baseline (429.047 us; speedup 1.0000x reference)
//
#include <hip/hip_runtime.h>
#include <hip/hip_cooperative_groups.h>

namespace cg = cooperative_groups;

#define N_ 32
#define C_ 256
#define G_ 16
#define HW_ 3136          // 56*56
#define HW4_ 784          // HW/4 in vf4 units; 784 = 12*64 + 16
#define EPS_ 1e-12f
#define RPB_ 4            // rows per block = waves per block
#define GRID_ (N_ * C_ / RPB_)   // 2048 = 256 CUs x 8 blocks

typedef float vf4 __attribute__((ext_vector_type(4)));
typedef float vf2 __attribute__((ext_vector_type(2)));

// Integer inputs may arrive as int32 or int64; group_sizes[1]==24 in int32
// layout, ==0 (high word of gs[0]) in int64 LE layout. Values < 2^31 so the
// low word is the value in int64 mode.
__device__ __forceinline__ int rd_int(const int* __restrict__ p, int i, bool is64) {
    return is64 ? p[2 * i] : p[i];
}

__device__ __forceinline__ void acc4(const vf4 v, float& s, float& s2) {
    s += v.x + v.y + v.z + v.w;
    s2 = fmaf(v.x, v.x, s2);
    s2 = fmaf(v.y, v.y, s2);
    s2 = fmaf(v.z, v.z, s2);
    s2 = fmaf(v.w, v.w, s2);
}

__device__ __forceinline__ vf4 aff(const vf4 v, float sc, float sh) {
    vf4 r;
    r.x = fmaf(v.x, sc, sh);
    r.y = fmaf(v.y, sc, sh);
    r.z = fmaf(v.z, sc, sh);
    r.w = fmaf(v.w, sc, sh);
    return r;
}

// ---------------------------------------------------------------------------
// v5. Lessons: v4 (2 kernels, 8 blk/CU, reg-batched loads) tied the old
// baseline at ~73 us kernel-sum (~2.8 TB/s effective) while the harness's own
// fillBuffer runs 6.8 TB/s with PLAIN stores. Every version so far used
// nontemporal stores on the output path -> prime suspect (nt bypasses normal
// L2 write handling; and it buys nothing: x + out = 196 MB < 256 MB L3).
// v5: plain stores; one cooperative kernel (grid.sync instead of kernel
// boundary; saves a launch+drain and restores counter visibility); one wave
// per row end-to-end: no LDS, no __syncthreads, stats derived in-wave.
// ---------------------------------------------------------------------------

__device__ __forceinline__ void row_reduce(
    const float* __restrict__ x, const int* __restrict__ indexes,
    bool is64, int row, int lane, float* __restrict__ rsums)
{
    const int src = rd_int(indexes, row, is64);
    const vf4* p = (const vf4*)x + (size_t)src * HW4_;

    float s = 0.f, q = 0.f;
    #pragma unroll
    for (int h = 0; h < 2; h++) {               // 2 batches x 6 loads in flight
        vf4 v0 = p[lane + (h * 6 + 0) * 64];
        vf4 v1 = p[lane + (h * 6 + 1) * 64];
        vf4 v2 = p[lane + (h * 6 + 2) * 64];
        vf4 v3 = p[lane + (h * 6 + 3) * 64];
        vf4 v4 = p[lane + (h * 6 + 4) * 64];
        vf4 v5 = p[lane + (h * 6 + 5) * 64];
        acc4(v0, s, q); acc4(v1, s, q); acc4(v2, s, q);
        acc4(v3, s, q); acc4(v4, s, q); acc4(v5, s, q);
    }
    if (lane < 16) {                            // 784 = 12*64 + 16 tail
        vf4 t = p[768 + lane];
        acc4(t, s, q);
    }
    #pragma unroll
    for (int off = 32; off > 0; off >>= 1) {
        s += __shfl_down(s, off);
        q += __shfl_down(q, off);
    }
    if (lane == 0) {
        vf2 r; r.x = s; r.y = q;
        ((vf2*)rsums)[row] = r;
    }
}

__device__ __forceinline__ void row_norm(
    const float* __restrict__ x, const int* __restrict__ indexes,
    const int* __restrict__ group_sizes,
    const float* __restrict__ weight, const float* __restrict__ bias,
    const float* __restrict__ rsums, float* __restrict__ out,
    bool is64, int row, int lane)
{
    const int j = row & (C_ - 1);
    const int n = row >> 8;

    // group of j + group start Pg via monotone prefix scan
    int g = 0, P = 0, Pg = 0;
    #pragma unroll
    for (int k = 0; k < G_; k++) {
        P += rd_int(group_sizes, k, is64);
        if (j >= P) { g++; Pg = P; }
    }
    const int gsz = rd_int(group_sizes, g, is64);

    // combine the group's contiguous per-row partials (gsz <= 32), in-wave
    float a = 0.f, b = 0.f;
    if (lane < gsz) {
        const vf2 pr = ((const vf2*)rsums)[n * C_ + Pg + lane];
        a = pr.x; b = pr.y;
    }
    #pragma unroll
    for (int off = 32; off > 0; off >>= 1) {
        a += __shfl_down(a, off);
        b += __shfl_down(b, off);
    }
    a = __shfl(a, 0);
    b = __shfl(b, 0);

    const float cnt = (float)gsz * (float)HW_;
    const float mu  = a / cnt;
    const float var = (b - mu * a) / (cnt - 1.0f);     // ddof=1, matches ref
    const float sc  = rsqrtf(var + EPS_) * weight[j];
    const float sh  = fmaf(-mu, sc, bias[j]);

    // normalize; write-back target is the SAME flat row (reverse permutation
    // is the inverse of the gather). PLAIN stores: out fits in L3 next to x.
    const int src = rd_int(indexes, row, is64);
    const vf4* p = (const vf4*)x + (size_t)src * HW4_;
    vf4*       o = (vf4*)out      + (size_t)src * HW4_;

    #pragma unroll
    for (int h = 0; h < 2; h++) {
        vf4 v0 = p[lane + (h * 6 + 0) * 64];
        vf4 v1 = p[lane + (h * 6 + 1) * 64];
        vf4 v2 = p[lane + (h * 6 + 2) * 64];
        vf4 v3 = p[lane + (h * 6 + 3) * 64];
        vf4 v4 = p[lane + (h * 6 + 4) * 64];
        vf4 v5 = p[lane + (h * 6 + 5) * 64];
        o[lane + (h * 6 + 0) * 64] = aff(v0, sc, sh);
        o[lane + (h * 6 + 1) * 64] = aff(v1, sc, sh);
        o[lane + (h * 6 + 2) * 64] = aff(v2, sc, sh);
        o[lane + (h * 6 + 3) * 64] = aff(v3, sc, sh);
        o[lane + (h * 6 + 4) * 64] = aff(v4, sc, sh);
        o[lane + (h * 6 + 5) * 64] = aff(v5, sc, sh);
    }
    if (lane < 16)
        o[768 + lane] = aff(p[768 + lane], sc, sh);
}

// ---- single cooperative kernel: phase1, grid sync, phase2 ------------------
__global__ __launch_bounds__(256, 8) void vgn_coop(
    const float* __restrict__ x, const int* __restrict__ indexes,
    const int* __restrict__ group_sizes,
    const float* __restrict__ weight, const float* __restrict__ bias,
    float* __restrict__ rsums, float* __restrict__ out)
{
    const bool is64 = (group_sizes[1] == 0);
    const int wave = threadIdx.x >> 6;
    const int lane = threadIdx.x & 63;
    const int row  = blockIdx.x * RPB_ + wave;

    row_reduce(x, indexes, is64, row, lane, rsums);
    cg::this_grid().sync();
    row_norm(x, indexes, group_sizes, weight, bias, rsums, out, is64, row, lane);
}

// ---- fallback pair (used only if cooperative launch is rejected) -----------
__global__ __launch_bounds__(256, 8) void vgn_p1(
    const float* __restrict__ x, const int* __restrict__ indexes,
    const int* __restrict__ group_sizes, float* __restrict__ rsums)
{
    const bool is64 = (group_sizes[1] == 0);
    const int row = blockIdx.x * RPB_ + (threadIdx.x >> 6);
    row_reduce(x, indexes, is64, row, threadIdx.x & 63, rsums);
}

__global__ __launch_bounds__(256, 8) void vgn_p2(
    const float* __restrict__ x, const int* __restrict__ indexes,
    const int* __restrict__ group_sizes,
    const float* __restrict__ weight, const float* __restrict__ bias,
    const float* __restrict__ rsums, float* __restrict__ out)
{
    const bool is64 = (group_sizes[1] == 0);
    const int row = blockIdx.x * RPB_ + (threadIdx.x >> 6);
    row_norm(x, indexes, group_sizes, weight, bias, rsums, out, is64,
             row, threadIdx.x & 63);
}

// ---------------------------------------------------------------------------
extern "C" void kernel_launch(void* const* d_in, const int* in_sizes, int n_in,
                              void* d_out, int out_size, void* d_ws, size_t ws_size,
                              hipStream_t stream) {
    const float* x           = (const float*)d_in[0];
    const float* weight      = (const float*)d_in[1];
    const float* bias        = (const float*)d_in[2];
    const int*   group_sizes = (const int*)  d_in[3];
    const int*   indexes     = (const int*)  d_in[4];
    // d_in[5] = reverse_indexes (unused: scatter target == gather source)

    float* rsums = (float*)d_ws;        // N_*C_ vf2 = 64 KB, fully written in
                                        // phase 1 (no init, no atomics)
    float* outp  = (float*)d_out;

    void* args[] = { (void*)&x, (void*)&indexes, (void*)&group_sizes,
                     (void*)&weight, (void*)&bias, (void*)&rsums, (void*)&outp };

    hipError_t err = hipLaunchCooperativeKernel(
        (const void*)vgn_coop, dim3(GRID_), dim3(256), args, 0, stream);

    if (err != hipSuccess) {            // fallback: plain 2-kernel pipeline
        vgn_p1<<<dim3(GRID_), dim3(256), 0, stream>>>(x, indexes, group_sizes,
                                                      rsums);
        vgn_p2<<<dim3(GRID_), dim3(256), 0, stream>>>(x, indexes, group_sizes,
                                                      weight, bias, rsums, outp);
    }
}

// Round 6
// 201.851 us; speedup vs baseline: 2.1256x; 2.1256x over previous
//
#include <hip/hip_runtime.h>

#define N_ 32
#define C_ 256
#define G_ 16
#define HW_ 3136          // 56*56
#define HW4_ 784          // HW/4 in vf4 units; 784 = 3*256 + 16
#define EPS_ 1e-12f

typedef float vf4 __attribute__((ext_vector_type(4)));
typedef float vf2 __attribute__((ext_vector_type(2)));

// Integer inputs may arrive as int32 or int64; group_sizes[1]==24 in int32
// layout, ==0 (high word of gs[0]) in int64 LE layout. Values < 2^31 so the
// low word is the value in int64 mode.
__device__ __forceinline__ int rd_int(const int* __restrict__ p, int i, bool is64) {
    return is64 ? p[2 * i] : p[i];
}

__device__ __forceinline__ void acc4(const vf4 v, float& s, float& s2) {
    s += v.x + v.y + v.z + v.w;
    s2 = fmaf(v.x, v.x, s2);
    s2 = fmaf(v.y, v.y, s2);
    s2 = fmaf(v.z, v.z, s2);
    s2 = fmaf(v.w, v.w, s2);
}

__device__ __forceinline__ vf4 aff(const vf4 v, float sc, float sh) {
    vf4 r;
    r.x = fmaf(v.x, sc, sh);
    r.y = fmaf(v.y, sc, sh);
    r.z = fmaf(v.z, sc, sh);
    r.w = fmaf(v.w, sc, sh);
    return r;
}

// ---------------------------------------------------------------------------
// v6 = v4 with ONE change: plain stores instead of nontemporal stores.
// (Resubmission — R5 bench was lost to a GPU acquisition timeout.)
//
// History: v4 (2 kernels, 4096 blk x 256 thr = 8 blk/CU, reg-batched loads,
// NT stores) = best measured, kernel-sum ~73 us. v5 (cooperative grid.sync)
// = 286 us/dispatch -- grid-wide sync costs 4x the useful work; coop is dead.
// The harness's own fillBuffer sustains 6.8 TB/s pure-write with PLAIN stores
// from 256-thread blocks; x + out = 196 MB < 256 MB L3, so writing through
// the cache cannot evict x. This round cleanly tests the NT-store hypothesis
// (v5 muddied it by changing two variables).
// ---------------------------------------------------------------------------

// Kernel 1: per permuted row pair: S / S2, plain stores to rsums[row*2+{0,1}].
__global__ __launch_bounds__(256, 8) void vgn_reduce(
    const float* __restrict__ x,
    const int*   __restrict__ indexes,
    const int*   __restrict__ group_sizes,
    float*       __restrict__ rsums)
{
    const bool is64 = (group_sizes[1] == 0);
    const int t  = threadIdx.x;
    const int r0 = blockIdx.x * 2;

    const int src0 = rd_int(indexes, r0,     is64);
    const int src1 = rd_int(indexes, r0 + 1, is64);
    const vf4* p0 = (const vf4*)x + (size_t)src0 * HW4_;
    const vf4* p1 = (const vf4*)x + (size_t)src1 * HW4_;

    // 6 unconditional + 2 tail loads, all issued before any consumption
    vf4 a0 = p0[t], b0 = p0[t + 256], c0 = p0[t + 512];
    vf4 a1 = p1[t], b1 = p1[t + 256], c1 = p1[t + 512];

    float sA = 0.f, qA = 0.f, sB = 0.f, qB = 0.f;
    if (t < 16) {                       // 784 = 3*256 + 16 tail
        vf4 d0 = p0[768 + t];
        vf4 d1 = p1[768 + t];
        acc4(d0, sA, qA);
        acc4(d1, sB, qB);
    }
    acc4(a0, sA, qA); acc4(b0, sA, qA); acc4(c0, sA, qA);
    acc4(a1, sB, qB); acc4(b1, sB, qB); acc4(c1, sB, qB);

    #pragma unroll
    for (int off = 32; off > 0; off >>= 1) {
        sA += __shfl_down(sA, off);
        qA += __shfl_down(qA, off);
        sB += __shfl_down(sB, off);
        qB += __shfl_down(qB, off);
    }

    __shared__ float red[4][4];         // [wave][val]
    if ((t & 63) == 0) {
        const int w = t >> 6;
        red[w][0] = sA; red[w][1] = qA; red[w][2] = sB; red[w][3] = qB;
    }
    __syncthreads();
    if (t < 4)                          // {S,S2} row0, {S,S2} row1
        rsums[r0 * 2 + t] = red[0][t] + red[1][t] + red[2][t] + red[3][t];
}

// Kernel 2: per permuted row pair: combine the group's contiguous per-row
// partials (gsz <= 32) into stats, then normalize + affine. Write-back target
// is the SAME flat row (reverse permutation is the inverse of the gather).
// x loads issued FIRST so the stats prologue hides under them. Plain stores.
__global__ __launch_bounds__(256, 8) void vgn_norm(
    const float* __restrict__ x,
    const int*   __restrict__ indexes,
    const int*   __restrict__ group_sizes,
    const float* __restrict__ weight,
    const float* __restrict__ bias,
    const float* __restrict__ rsums,
    float*       __restrict__ out)
{
    const bool is64 = (group_sizes[1] == 0);
    const int t  = threadIdx.x;
    const int r0 = blockIdx.x * 2;
    const int n  = r0 >> 8;

    const int src0 = rd_int(indexes, r0,     is64);
    const int src1 = rd_int(indexes, r0 + 1, is64);
    const vf4* p0 = (const vf4*)x + (size_t)src0 * HW4_;
    const vf4* p1 = (const vf4*)x + (size_t)src1 * HW4_;
    vf4* o0 = (vf4*)out + (size_t)src0 * HW4_;
    vf4* o1 = (vf4*)out + (size_t)src1 * HW4_;

    // issue the streaming loads before the stats prologue
    vf4 a0 = p0[t], b0 = p0[t + 256], c0 = p0[t + 512];
    vf4 a1 = p1[t], b1 = p1[t + 256], c1 = p1[t + 512];
    vf4 d0, d1;
    const bool tail = (t < 16);
    if (tail) { d0 = p0[768 + t]; d1 = p1[768 + t]; }

    __shared__ float sScale[2], sShift[2];
    if (t < 64) {                       // half-wave per row
        const int half = t >> 5;
        const int l    = t & 31;
        const int j    = (r0 + half) & 255;
        int g = 0, P = 0, Pg = 0;
        #pragma unroll
        for (int k = 0; k < G_; k++) {
            P += rd_int(group_sizes, k, is64);
            if (j >= P) { g++; Pg = P; }
        }
        const int gsz = rd_int(group_sizes, g, is64);
        float a = 0.f, b = 0.f;
        if (l < gsz) {
            const vf2 pr = ((const vf2*)rsums)[n * C_ + Pg + l];
            a = pr.x; b = pr.y;
        }
        #pragma unroll
        for (int off = 16; off > 0; off >>= 1) {
            a += __shfl_down(a, off, 32);
            b += __shfl_down(b, off, 32);
        }
        if (l == 0) {
            const float cnt = (float)gsz * (float)HW_;
            const float mu  = a / cnt;
            const float var = (b - mu * a) / (cnt - 1.0f);   // ddof=1
            const float ivr = rsqrtf(var + EPS_);
            const float sc  = ivr * weight[j];
            sScale[half] = sc;
            sShift[half] = fmaf(-mu, sc, bias[j]);
        }
    }
    __syncthreads();

    const float sc0 = sScale[0], sh0 = sShift[0];
    const float sc1 = sScale[1], sh1 = sShift[1];

    o0[t]       = aff(a0, sc0, sh0);
    o0[t + 256] = aff(b0, sc0, sh0);
    o0[t + 512] = aff(c0, sc0, sh0);
    o1[t]       = aff(a1, sc1, sh1);
    o1[t + 256] = aff(b1, sc1, sh1);
    o1[t + 512] = aff(c1, sc1, sh1);
    if (tail) {
        o0[768 + t] = aff(d0, sc0, sh0);
        o1[768 + t] = aff(d1, sc1, sh1);
    }
}

// ---------------------------------------------------------------------------
extern "C" void kernel_launch(void* const* d_in, const int* in_sizes, int n_in,
                              void* d_out, int out_size, void* d_ws, size_t ws_size,
                              hipStream_t stream) {
    const float* x           = (const float*)d_in[0];
    const float* weight      = (const float*)d_in[1];
    const float* bias        = (const float*)d_in[2];
    const int*   group_sizes = (const int*)  d_in[3];
    const int*   indexes     = (const int*)  d_in[4];
    // d_in[5] = reverse_indexes (unused: scatter target == gather source)

    float* rsums = (float*)d_ws;        // N_*C_*2 floats = 64 KB, fully written
                                        // by vgn_reduce (no init, no atomics)

    dim3 grid(N_ * C_ / 2), block(256); // 4096 blocks: 8/CU, 32 waves/CU
    vgn_reduce<<<grid, block, 0, stream>>>(x, indexes, group_sizes, rsums);
    vgn_norm  <<<grid, block, 0, stream>>>(x, indexes, group_sizes,
                                           weight, bias, rsums, (float*)d_out);
}